// Round 6
// baseline (79.927 us; speedup 1.0000x reference)
//
#include <hip/hip_runtime.h>

typedef __attribute__((ext_vector_type(8))) short short8;
typedef __attribute__((ext_vector_type(4))) short short4v;
typedef __attribute__((ext_vector_type(4))) float f32x4;

#define MFMA_16x16x32_BF16(A, B, C) __builtin_amdgcn_mfma_f32_16x16x32_bf16(A, B, C, 0, 0, 0)

// float -> bf16 bits, round-to-nearest-even (inputs always finite here)
__device__ __forceinline__ unsigned short f2bf(float x) {
    unsigned int u = __builtin_bit_cast(unsigned int, x);
    u = (u + 0x7FFFu + ((u >> 16) & 1u)) >> 16;
    return (unsigned short)u;
}

// ---------------------------------------------------------------------------
// Kernel 1: pack Wk|Wq|Wv (fp32 [1024][64]) into MFMA-FRAGMENT-TILED bf16:
//   Wf[((kt*12 + c)*64 + lane)*8 + e] = W[k = 32*kt + 8*(lane>>4) + e][n = 16*c + (lane&15)]
// (n in [0,192) spans K|Q|V).  A B-fragment load in proj is then ONE
// contiguous 1-KB wave read — no address scatter, minimal L2 requests.
// ---------------------------------------------------------------------------
__global__ __launch_bounds__(64) void wconv_kernel(const float* __restrict__ Wk,
                                                   const float* __restrict__ Wq,
                                                   const float* __restrict__ Wv,
                                                   unsigned short* __restrict__ Wf) {
    const int kt = blockIdx.x;                     // 0..31
    const int c = blockIdx.y;                      // 0..11
    const int lane = threadIdx.x;
    const int lr = lane & 15, g = lane >> 4;
    const int n = 16 * c + lr;
    const float* W = (n < 64) ? Wk : (n < 128) ? Wq : Wv;
    const int col = n & 63;
    const int k0 = 32 * kt + 8 * g;
    short8 o;
#pragma unroll
    for (int e = 0; e < 8; ++e)
        o[e] = (short)f2bf(W[(size_t)(k0 + e) * 64 + col]);
    *(short8*)&Wf[(size_t)((kt * 12 + c) * 64 + lane) * 8] = o;
}

// ---------------------------------------------------------------------------
// Kernel 2: QKV projection, streaming fragment GEMM v5 — no LDS, no barriers,
// no hand-rolled rings.  4096 single-wave blocks (4 waves/SIMD): block
// (rt = bid>>2, cw = bid&3) computes rows 16*rt..+15, col-tiles 3*cw..3*cw+2
// of the [16384][192] output over full K=1024 (32 fully-unrolled steps).
// ~50 live VGPRs; the compiler hoists the independent A/B loads several
// steps ahead (launch_bounds caps at 128 VGPR for 4 waves/SIMD).
// Consecutive bids share the X row-strip -> re-reads are L2/L3 hits.
// Outputs: Kb/Qb row-major [16384][64]; V transposed Vtg[b][64][2048].
// ---------------------------------------------------------------------------
__global__ __launch_bounds__(64, 4) void proj_kernel(const float* __restrict__ X,
                                                     const unsigned short* __restrict__ Wf,
                                                     unsigned short* __restrict__ Kb,
                                                     unsigned short* __restrict__ Qb,
                                                     unsigned short* __restrict__ Vtg) {
    const int lane = threadIdx.x;
    const int lr = lane & 15, g = lane >> 4;
    const int rt = blockIdx.x >> 2, cw = blockIdx.x & 3;
    const int r0 = rt * 16;
    const int c0 = cw * 3;                         // first of 3 col-tiles

    f32x4 acc[3] = {};
    const float* xb = X + (size_t)(r0 + lr) * 1024 + 8 * g;
    const unsigned short* wp0 = Wf + (size_t)c0 * 512 + lane * 8;

#pragma unroll
    for (int s = 0; s < 32; ++s) {
        float4 a0 = *(const float4*)(xb + 32 * s);
        float4 a1 = *(const float4*)(xb + 32 * s + 4);
        const unsigned short* wp = wp0 + (size_t)s * 12 * 512;
        short8 b0 = *(const short8*)(wp);
        short8 b1 = *(const short8*)(wp + 512);
        short8 b2 = *(const short8*)(wp + 1024);
        short8 af;
        af[0] = (short)f2bf(a0.x); af[1] = (short)f2bf(a0.y);
        af[2] = (short)f2bf(a0.z); af[3] = (short)f2bf(a0.w);
        af[4] = (short)f2bf(a1.x); af[5] = (short)f2bf(a1.y);
        af[6] = (short)f2bf(a1.z); af[7] = (short)f2bf(a1.w);
        acc[0] = MFMA_16x16x32_BF16(af, b0, acc[0]);
        acc[1] = MFMA_16x16x32_BF16(af, b1, acc[1]);
        acc[2] = MFMA_16x16x32_BF16(af, b2, acc[2]);
    }

    // ---- epilogue: C/D layout col = lane&15 (W-col), row = 4*(lane>>4)+reg ----
    const int bb = r0 >> 11;                      // batch
    const int sb0 = (r0 & 2047) + 4 * g;          // s within batch (+r)
    const int row = r0 + 4 * g;
#pragma unroll
    for (int i = 0; i < 3; ++i) {
        const int cg = c0 + i;
        if (cg < 4) {
#pragma unroll
            for (int r = 0; r < 4; ++r)
                Kb[(size_t)(row + r) * 64 + 16 * cg + lr] = f2bf(acc[i][r]);
        } else if (cg < 8) {
#pragma unroll
            for (int r = 0; r < 4; ++r)
                Qb[(size_t)(row + r) * 64 + 16 * (cg - 4) + lr] = f2bf(acc[i][r]);
        } else {
            const int h = 16 * (cg - 8) + lr;
#pragma unroll
            for (int r = 0; r < 4; ++r)
                Vtg[(size_t)bb * 64 * 2048 + (size_t)h * 2048 + sb0 + r] = f2bf(acc[i][r]);
        }
    }
}

// ---------------------------------------------------------------------------
// Kernel 3: causal flash attention, band-pair blocks (measured-best version,
// unchanged).  Block = bands {63-p (hi), p (lo)} of 32 q-rows each ->
// exactly 65 kv-steps per block.  8 waves split the 65 steps contiguously;
// K and V^T fragments load DIRECTLY from global (L2-resident) -> no LDS, no
// barriers in the main loop.  Partials merged in LDS at the end.
// ---------------------------------------------------------------------------
__global__ __launch_bounds__(512, 2) void attn_kernel(const unsigned short* __restrict__ Kb,
                                                      const unsigned short* __restrict__ Qb,
                                                      const unsigned short* __restrict__ Vtg,
                                                      float* __restrict__ out) {
    __shared__ __attribute__((aligned(16))) float Pacc[16][32][68];  // [slot][q][h] pad 68
    __shared__ float Pml[2][16][32];                                 // m / l per slot,q

    const int t = threadIdx.x;
    const int w = t >> 6, lane = t & 63;
    const int lr = lane & 15, g = lane >> 4;
    const int p = blockIdx.x, b = blockIdx.y;
    const int nhi = 64 - p;                      // steps for hi band
    const int q0h = (63 - p) * 32, q0l = p * 32;
    const size_t rowbase = (size_t)b * 2048;
    const size_t vbase = (size_t)b * 64 * 2048;
    const float NEG_INF = -__builtin_inff();
    const float SCALE2 = 0.03125f * 1.4426950408889634f;   // d^-0.5 * log2(e)

    // Q fragments (B-operand): [sub][hh]
    short8 qfH[2][2], qfL[2][2];
#pragma unroll
    for (int sub = 0; sub < 2; ++sub)
#pragma unroll
        for (int hh = 0; hh < 2; ++hh) {
            qfH[sub][hh] = *(const short8*)(Qb + (rowbase + q0h + 16 * sub + lr) * 64 + 32 * hh + 8 * g);
            qfL[sub][hh] = *(const short8*)(Qb + (rowbase + q0l + 16 * sub + lr) * 64 + 32 * hh + 8 * g);
        }

    f32x4 accH[2][4] = {}, accL[2][4] = {};
    float mH[2] = {NEG_INF, NEG_INF}, mL[2] = {NEG_INF, NEG_INF};
    float lH[2] = {0.f, 0.f}, lL[2] = {0.f, 0.f};

    const int s0 = (w * 65) >> 3, s1 = ((w + 1) * 65) >> 3;

    auto step = [&](int kv0, int q0, const short8 (&qf)[2][2],
                    f32x4 (&acc)[2][4], float (&m2)[2], float (&ls)[2]) {
        // K A-frags direct from global: row kv0+16f+lr, cols 32hh+8g (16B)
        short8 kf[2][2];
#pragma unroll
        for (int f = 0; f < 2; ++f)
#pragma unroll
            for (int hh = 0; hh < 2; ++hh)
                kf[f][hh] = *(const short8*)(Kb + (rowbase + kv0 + 16 * f + lr) * 64 + 32 * hh + 8 * g);
        // V^T A-frags direct from Vtg: row h=16fh+lr, kv cols 4g.. / 16+4g..
        short8 vf[4];
#pragma unroll
        for (int fh = 0; fh < 4; ++fh) {
            const unsigned short* vp = Vtg + vbase + (size_t)(16 * fh + lr) * 2048 + kv0 + 4 * g;
            short4v v0 = *(const short4v*)vp;
            short4v v1 = *(const short4v*)(vp + 16);
            short8 vv;
            vv[0] = v0[0]; vv[1] = v0[1]; vv[2] = v0[2]; vv[3] = v0[3];
            vv[4] = v1[0]; vv[5] = v1[1]; vv[6] = v1[2]; vv[7] = v1[3];
            vf[fh] = vv;
        }
#pragma unroll
        for (int sub = 0; sub < 2; ++sub) {
            f32x4 sv[2];
#pragma unroll
            for (int f = 0; f < 2; ++f) {
                f32x4 x = {};
                x = MFMA_16x16x32_BF16(kf[f][0], qf[sub][0], x);
                x = MFMA_16x16x32_BF16(kf[f][1], qf[sub][1], x);
                sv[f] = x;
            }
            const int q = q0 + 16 * sub + lr;
            float pvv[8], tmax = NEG_INF;
#pragma unroll
            for (int f = 0; f < 2; ++f)
#pragma unroll
                for (int r = 0; r < 4; ++r) {
                    int kp = kv0 + 16 * f + 4 * g + r;
                    float sc = sv[f][r] * SCALE2;
                    sc = (kp <= q) ? sc : NEG_INF;
                    pvv[4 * f + r] = sc;
                    tmax = fmaxf(tmax, sc);
                }
            tmax = fmaxf(tmax, __shfl_xor(tmax, 16));
            tmax = fmaxf(tmax, __shfl_xor(tmax, 32));
            float mnew = fmaxf(m2[sub], tmax);     // finite: kv0 <= q0 <= q always
            float alpha = exp2f(m2[sub] - mnew);
            float psum = 0.f;
            short8 pf;
#pragma unroll
            for (int e = 0; e < 8; ++e) {
                float pe = exp2f(pvv[e] - mnew);
                psum += pe;
                pf[e] = (short)f2bf(pe);
            }
            psum += __shfl_xor(psum, 16);
            psum += __shfl_xor(psum, 32);
            ls[sub] = ls[sub] * alpha + psum;
            m2[sub] = mnew;
#pragma unroll
            for (int fh = 0; fh < 4; ++fh) {
                acc[sub][fh][0] *= alpha; acc[sub][fh][1] *= alpha;
                acc[sub][fh][2] *= alpha; acc[sub][fh][3] *= alpha;
                acc[sub][fh] = MFMA_16x16x32_BF16(vf[fh], pf, acc[sub][fh]);
            }
        }
    };

    const int ehi = (s1 < nhi) ? s1 : nhi;
    for (int s = s0; s < ehi; ++s) step(s * 32, q0h, qfH, accH, mH, lH);
    const int slo = (s0 > nhi) ? s0 : nhi;
    for (int s = slo; s < s1; ++s) step((s - nhi) * 32, q0l, qfL, accL, mL, lL);

    // ---- write partials to LDS ----
#pragma unroll
    for (int bnd = 0; bnd < 2; ++bnd) {
        const f32x4 (&acc)[2][4] = bnd ? accL : accH;
        const float (&m2)[2] = bnd ? mL : mH;
        const float (&ls)[2] = bnd ? lL : lH;
        const int slot = bnd * 8 + w;
#pragma unroll
        for (int sub = 0; sub < 2; ++sub) {
#pragma unroll
            for (int fh = 0; fh < 4; ++fh)
                *(f32x4*)&Pacc[slot][16 * sub + lr][16 * fh + 4 * g] = acc[sub][fh];
            if (g == 0) {
                Pml[0][slot][16 * sub + lr] = m2[sub];
                Pml[1][slot][16 * sub + lr] = ls[sub];
            }
        }
    }
    __syncthreads();

    // ---- combine: 512 thr -> 2 bands x 32 q x 8 h-groups ----
    {
        const int tb = t >> 8, t2 = t & 255;
        const int qq = t2 & 31, hb = (t2 >> 5) * 8;
        float mw[8], M = NEG_INF;
#pragma unroll
        for (int wv = 0; wv < 8; ++wv) {
            mw[wv] = Pml[0][tb * 8 + wv][qq];
            M = fmaxf(M, mw[wv]);
        }
        float wgt[8], L = 0.f;
#pragma unroll
        for (int wv = 0; wv < 8; ++wv) {
            wgt[wv] = exp2f(mw[wv] - M);           // exp2(-inf)=0 for idle waves
            L += wgt[wv] * Pml[1][tb * 8 + wv][qq];
        }
        f32x4 o0 = {}, o1 = {};
#pragma unroll
        for (int wv = 0; wv < 8; ++wv) {
            f32x4 a0 = *(const f32x4*)&Pacc[tb * 8 + wv][qq][hb];
            f32x4 a1 = *(const f32x4*)&Pacc[tb * 8 + wv][qq][hb + 4];
            o0 += wgt[wv] * a0;
            o1 += wgt[wv] * a1;
        }
        const float invL = 1.f / L;
        o0 *= invL; o1 *= invL;
        const int q0 = tb ? q0l : q0h;
        float* op = out + (rowbase + q0 + qq) * 64 + hb;
        *(f32x4*)op = o0;
        *(f32x4*)(op + 4) = o1;
    }
}

// ---------------------------------------------------------------------------
extern "C" void kernel_launch(void* const* d_in, const int* in_sizes, int n_in,
                              void* d_out, int out_size, void* d_ws, size_t ws_size,
                              hipStream_t stream) {
    const float* X  = (const float*)d_in[0];
    const float* Wk = (const float*)d_in[1];
    const float* Wq = (const float*)d_in[2];
    const float* Wv = (const float*)d_in[3];

    unsigned short* Wf  = (unsigned short*)d_ws;       // 32*12*64*8 = 196608 bf16
    unsigned short* Kb  = Wf + 196608;                 // [16384][64] bf16
    unsigned short* Qb  = Kb + 16384 * 64;             // [16384][64] bf16
    unsigned short* Vtg = Qb + 16384 * 64;             // [8][64][2048] bf16 (V^T)
    float* out = (float*)d_out;

    wconv_kernel<<<dim3(32, 12), dim3(64), 0, stream>>>(Wk, Wq, Wv, Wf);
    proj_kernel<<<dim3(4096), dim3(64), 0, stream>>>(X, Wf, Kb, Qb, Vtg);
    attn_kernel<<<dim3(32, 8), dim3(512), 0, stream>>>(Kb, Qb, Vtg, out);
}

// Round 7
// 79.129 us; speedup vs baseline: 1.0101x; 1.0101x over previous
//
#include <hip/hip_runtime.h>

typedef __attribute__((ext_vector_type(8))) short short8;
typedef __attribute__((ext_vector_type(4))) short short4v;
typedef __attribute__((ext_vector_type(4))) float f32x4;

#define MFMA_16x16x32_BF16(A, B, C) __builtin_amdgcn_mfma_f32_16x16x32_bf16(A, B, C, 0, 0, 0)

// float -> bf16 bits, round-to-nearest-even (inputs always finite here)
__device__ __forceinline__ unsigned short f2bf(float x) {
    unsigned int u = __builtin_bit_cast(unsigned int, x);
    u = (u + 0x7FFFu + ((u >> 16) & 1u)) >> 16;
    return (unsigned short)u;
}

// ---------------------------------------------------------------------------
// Kernel 1: pack Wk|Wq|Wv (fp32 [1024][64]) into MFMA-FRAGMENT-TILED bf16:
//   Wf[((kt*12 + c)*64 + lane)*8 + e] = W[k = 32*kt + 8*(lane>>4) + e][n = 16*c + (lane&15)]
// A B-fragment load in proj is then ONE contiguous 1-KB wave read.
// ---------------------------------------------------------------------------
__global__ __launch_bounds__(64) void wconv_kernel(const float* __restrict__ Wk,
                                                   const float* __restrict__ Wq,
                                                   const float* __restrict__ Wv,
                                                   unsigned short* __restrict__ Wf) {
    const int kt = blockIdx.x;                     // 0..31
    const int c = blockIdx.y;                      // 0..11
    const int lane = threadIdx.x;
    const int lr = lane & 15, g = lane >> 4;
    const int n = 16 * c + lr;
    const float* W = (n < 64) ? Wk : (n < 128) ? Wq : Wv;
    const int col = n & 63;
    const int k0 = 32 * kt + 8 * g;
    short8 o;
#pragma unroll
    for (int e = 0; e < 8; ++e)
        o[e] = (short)f2bf(W[(size_t)(k0 + e) * 64 + col]);
    *(short8*)&Wf[(size_t)((kt * 12 + c) * 64 + lane) * 8] = o;
}

// ---------------------------------------------------------------------------
// Kernel 2: QKV projection, streaming fragment GEMM v6.
// v5 + the two fixes the counters demanded:
//  (1) explicit 4-deep static register ring (named slots, unroll x4) forces
//      batched loads: STEP(i) then ISSUE(i, s+4) -> use->reissue distance of
//      3 steps; in-order vmcnt waits only count the 15 younger loads.
//      (v5's VGPR_Count=32 proved the compiler serialized the loads.)
//  (2) XCD-affinity swizzle: bid = ((sg*4+cw)<<3)|low3, rt = sg*8+low3 ->
//      the 4 col-waves of a row-strip share one XCD and are dispatch-adjacent
//      -> X re-reads hit that XCD's L2 (v5 FETCH was 2x X).
// Block = 1 wave: rows 16*rt..+15, col-tiles 3*cw..3*cw+2, full K=1024.
// Outputs: Kb/Qb row-major [16384][64]; V transposed Vtg[b][64][2048].
// ---------------------------------------------------------------------------
__global__ __launch_bounds__(64, 4) void proj_kernel(const float* __restrict__ X,
                                                     const unsigned short* __restrict__ Wf,
                                                     unsigned short* __restrict__ Kb,
                                                     unsigned short* __restrict__ Qb,
                                                     unsigned short* __restrict__ Vtg) {
    const int lane = threadIdx.x;
    const int lr = lane & 15, g = lane >> 4;
    const int low3 = blockIdx.x & 7, hi = blockIdx.x >> 3;
    const int cw = hi & 3, sg = hi >> 2;
    const int rt = sg * 8 + low3;                  // row-strip 0..1023
    const int r0 = rt * 16;
    const int c0 = cw * 3;                         // first of 3 col-tiles

    f32x4 acc[3] = {};
    float4 Aa[4][2];                               // A ring [slot][half] — static only
    short8 Bb[4][3];                               // B ring [slot][coltile]

    const float* xb = X + (size_t)(r0 + lr) * 1024 + 8 * g;
    const unsigned short* wp0 = Wf + (size_t)c0 * 512 + lane * 8;

#define ISSUE(SL, S)                                                        \
    {                                                                       \
        const float* xp = xb + 32 * (S);                                    \
        Aa[SL][0] = *(const float4*)xp;                                     \
        Aa[SL][1] = *(const float4*)(xp + 4);                               \
        const unsigned short* wp = wp0 + (size_t)(S) * 6144;                \
        Bb[SL][0] = *(const short8*)(wp);                                   \
        Bb[SL][1] = *(const short8*)(wp + 512);                             \
        Bb[SL][2] = *(const short8*)(wp + 1024);                            \
    }
#define STEP(SL)                                                            \
    {                                                                       \
        float4 v0 = Aa[SL][0], v1 = Aa[SL][1];                              \
        short8 af;                                                          \
        af[0] = (short)f2bf(v0.x); af[1] = (short)f2bf(v0.y);               \
        af[2] = (short)f2bf(v0.z); af[3] = (short)f2bf(v0.w);               \
        af[4] = (short)f2bf(v1.x); af[5] = (short)f2bf(v1.y);               \
        af[6] = (short)f2bf(v1.z); af[7] = (short)f2bf(v1.w);               \
        acc[0] = MFMA_16x16x32_BF16(af, Bb[SL][0], acc[0]);                 \
        acc[1] = MFMA_16x16x32_BF16(af, Bb[SL][1], acc[1]);                 \
        acc[2] = MFMA_16x16x32_BF16(af, Bb[SL][2], acc[2]);                 \
    }

    ISSUE(0, 0) ISSUE(1, 1) ISSUE(2, 2) ISSUE(3, 3)

    for (int j = 0; j < 7; ++j) {                  // steps 0..27 with reissue
        STEP(0) ISSUE(0, 4 * j + 4)
        STEP(1) ISSUE(1, 4 * j + 5)
        STEP(2) ISSUE(2, 4 * j + 6)
        STEP(3) ISSUE(3, 4 * j + 7)
    }
    STEP(0) STEP(1) STEP(2) STEP(3)                // steps 28..31
#undef STEP
#undef ISSUE

    // ---- epilogue: C/D layout col = lane&15 (W-col), row = 4*(lane>>4)+reg ----
    const int bb = r0 >> 11;                      // batch
    const int sb0 = (r0 & 2047) + 4 * g;          // s within batch (+r)
    const int row = r0 + 4 * g;
#pragma unroll
    for (int i = 0; i < 3; ++i) {
        const int cg = c0 + i;
        if (cg < 4) {
#pragma unroll
            for (int r = 0; r < 4; ++r)
                Kb[(size_t)(row + r) * 64 + 16 * cg + lr] = f2bf(acc[i][r]);
        } else if (cg < 8) {
#pragma unroll
            for (int r = 0; r < 4; ++r)
                Qb[(size_t)(row + r) * 64 + 16 * (cg - 4) + lr] = f2bf(acc[i][r]);
        } else {
            const int h = 16 * (cg - 8) + lr;
#pragma unroll
            for (int r = 0; r < 4; ++r)
                Vtg[(size_t)bb * 64 * 2048 + (size_t)h * 2048 + sb0 + r] = f2bf(acc[i][r]);
        }
    }
}

// ---------------------------------------------------------------------------
// Kernel 3: causal flash attention, band-pair blocks (measured-best version,
// unchanged).  Block = bands {63-p (hi), p (lo)} of 32 q-rows each ->
// exactly 65 kv-steps per block.  8 waves split the 65 steps contiguously;
// K and V^T fragments load DIRECTLY from global (L2-resident) -> no LDS, no
// barriers in the main loop.  Partials merged in LDS at the end.
// ---------------------------------------------------------------------------
__global__ __launch_bounds__(512, 2) void attn_kernel(const unsigned short* __restrict__ Kb,
                                                      const unsigned short* __restrict__ Qb,
                                                      const unsigned short* __restrict__ Vtg,
                                                      float* __restrict__ out) {
    __shared__ __attribute__((aligned(16))) float Pacc[16][32][68];  // [slot][q][h] pad 68
    __shared__ float Pml[2][16][32];                                 // m / l per slot,q

    const int t = threadIdx.x;
    const int w = t >> 6, lane = t & 63;
    const int lr = lane & 15, g = lane >> 4;
    const int p = blockIdx.x, b = blockIdx.y;
    const int nhi = 64 - p;                      // steps for hi band
    const int q0h = (63 - p) * 32, q0l = p * 32;
    const size_t rowbase = (size_t)b * 2048;
    const size_t vbase = (size_t)b * 64 * 2048;
    const float NEG_INF = -__builtin_inff();
    const float SCALE2 = 0.03125f * 1.4426950408889634f;   // d^-0.5 * log2(e)

    // Q fragments (B-operand): [sub][hh]
    short8 qfH[2][2], qfL[2][2];
#pragma unroll
    for (int sub = 0; sub < 2; ++sub)
#pragma unroll
        for (int hh = 0; hh < 2; ++hh) {
            qfH[sub][hh] = *(const short8*)(Qb + (rowbase + q0h + 16 * sub + lr) * 64 + 32 * hh + 8 * g);
            qfL[sub][hh] = *(const short8*)(Qb + (rowbase + q0l + 16 * sub + lr) * 64 + 32 * hh + 8 * g);
        }

    f32x4 accH[2][4] = {}, accL[2][4] = {};
    float mH[2] = {NEG_INF, NEG_INF}, mL[2] = {NEG_INF, NEG_INF};
    float lH[2] = {0.f, 0.f}, lL[2] = {0.f, 0.f};

    const int s0 = (w * 65) >> 3, s1 = ((w + 1) * 65) >> 3;

    auto step = [&](int kv0, int q0, const short8 (&qf)[2][2],
                    f32x4 (&acc)[2][4], float (&m2)[2], float (&ls)[2]) {
        // K A-frags direct from global: row kv0+16f+lr, cols 32hh+8g (16B)
        short8 kf[2][2];
#pragma unroll
        for (int f = 0; f < 2; ++f)
#pragma unroll
            for (int hh = 0; hh < 2; ++hh)
                kf[f][hh] = *(const short8*)(Kb + (rowbase + kv0 + 16 * f + lr) * 64 + 32 * hh + 8 * g);
        // V^T A-frags direct from Vtg: row h=16fh+lr, kv cols 4g.. / 16+4g..
        short8 vf[4];
#pragma unroll
        for (int fh = 0; fh < 4; ++fh) {
            const unsigned short* vp = Vtg + vbase + (size_t)(16 * fh + lr) * 2048 + kv0 + 4 * g;
            short4v v0 = *(const short4v*)vp;
            short4v v1 = *(const short4v*)(vp + 16);
            short8 vv;
            vv[0] = v0[0]; vv[1] = v0[1]; vv[2] = v0[2]; vv[3] = v0[3];
            vv[4] = v1[0]; vv[5] = v1[1]; vv[6] = v1[2]; vv[7] = v1[3];
            vf[fh] = vv;
        }
#pragma unroll
        for (int sub = 0; sub < 2; ++sub) {
            f32x4 sv[2];
#pragma unroll
            for (int f = 0; f < 2; ++f) {
                f32x4 x = {};
                x = MFMA_16x16x32_BF16(kf[f][0], qf[sub][0], x);
                x = MFMA_16x16x32_BF16(kf[f][1], qf[sub][1], x);
                sv[f] = x;
            }
            const int q = q0 + 16 * sub + lr;
            float pvv[8], tmax = NEG_INF;
#pragma unroll
            for (int f = 0; f < 2; ++f)
#pragma unroll
                for (int r = 0; r < 4; ++r) {
                    int kp = kv0 + 16 * f + 4 * g + r;
                    float sc = sv[f][r] * SCALE2;
                    sc = (kp <= q) ? sc : NEG_INF;
                    pvv[4 * f + r] = sc;
                    tmax = fmaxf(tmax, sc);
                }
            tmax = fmaxf(tmax, __shfl_xor(tmax, 16));
            tmax = fmaxf(tmax, __shfl_xor(tmax, 32));
            float mnew = fmaxf(m2[sub], tmax);     // finite: kv0 <= q0 <= q always
            float alpha = exp2f(m2[sub] - mnew);
            float psum = 0.f;
            short8 pf;
#pragma unroll
            for (int e = 0; e < 8; ++e) {
                float pe = exp2f(pvv[e] - mnew);
                psum += pe;
                pf[e] = (short)f2bf(pe);
            }
            psum += __shfl_xor(psum, 16);
            psum += __shfl_xor(psum, 32);
            ls[sub] = ls[sub] * alpha + psum;
            m2[sub] = mnew;
#pragma unroll
            for (int fh = 0; fh < 4; ++fh) {
                acc[sub][fh][0] *= alpha; acc[sub][fh][1] *= alpha;
                acc[sub][fh][2] *= alpha; acc[sub][fh][3] *= alpha;
                acc[sub][fh] = MFMA_16x16x32_BF16(vf[fh], pf, acc[sub][fh]);
            }
        }
    };

    const int ehi = (s1 < nhi) ? s1 : nhi;
    for (int s = s0; s < ehi; ++s) step(s * 32, q0h, qfH, accH, mH, lH);
    const int slo = (s0 > nhi) ? s0 : nhi;
    for (int s = slo; s < s1; ++s) step((s - nhi) * 32, q0l, qfL, accL, mL, lL);

    // ---- write partials to LDS ----
#pragma unroll
    for (int bnd = 0; bnd < 2; ++bnd) {
        const f32x4 (&acc)[2][4] = bnd ? accL : accH;
        const float (&m2)[2] = bnd ? mL : mH;
        const float (&ls)[2] = bnd ? lL : lH;
        const int slot = bnd * 8 + w;
#pragma unroll
        for (int sub = 0; sub < 2; ++sub) {
#pragma unroll
            for (int fh = 0; fh < 4; ++fh)
                *(f32x4*)&Pacc[slot][16 * sub + lr][16 * fh + 4 * g] = acc[sub][fh];
            if (g == 0) {
                Pml[0][slot][16 * sub + lr] = m2[sub];
                Pml[1][slot][16 * sub + lr] = ls[sub];
            }
        }
    }
    __syncthreads();

    // ---- combine: 512 thr -> 2 bands x 32 q x 8 h-groups ----
    {
        const int tb = t >> 8, t2 = t & 255;
        const int qq = t2 & 31, hb = (t2 >> 5) * 8;
        float mw[8], M = NEG_INF;
#pragma unroll
        for (int wv = 0; wv < 8; ++wv) {
            mw[wv] = Pml[0][tb * 8 + wv][qq];
            M = fmaxf(M, mw[wv]);
        }
        float wgt[8], L = 0.f;
#pragma unroll
        for (int wv = 0; wv < 8; ++wv) {
            wgt[wv] = exp2f(mw[wv] - M);           // exp2(-inf)=0 for idle waves
            L += wgt[wv] * Pml[1][tb * 8 + wv][qq];
        }
        f32x4 o0 = {}, o1 = {};
#pragma unroll
        for (int wv = 0; wv < 8; ++wv) {
            f32x4 a0 = *(const f32x4*)&Pacc[tb * 8 + wv][qq][hb];
            f32x4 a1 = *(const f32x4*)&Pacc[tb * 8 + wv][qq][hb + 4];
            o0 += wgt[wv] * a0;
            o1 += wgt[wv] * a1;
        }
        const float invL = 1.f / L;
        o0 *= invL; o1 *= invL;
        const int q0 = tb ? q0l : q0h;
        float* op = out + (rowbase + q0 + qq) * 64 + hb;
        *(f32x4*)op = o0;
        *(f32x4*)(op + 4) = o1;
    }
}

// ---------------------------------------------------------------------------
extern "C" void kernel_launch(void* const* d_in, const int* in_sizes, int n_in,
                              void* d_out, int out_size, void* d_ws, size_t ws_size,
                              hipStream_t stream) {
    const float* X  = (const float*)d_in[0];
    const float* Wk = (const float*)d_in[1];
    const float* Wq = (const float*)d_in[2];
    const float* Wv = (const float*)d_in[3];

    unsigned short* Wf  = (unsigned short*)d_ws;       // 32*12*64*8 = 196608 bf16
    unsigned short* Kb  = Wf + 196608;                 // [16384][64] bf16
    unsigned short* Qb  = Kb + 16384 * 64;             // [16384][64] bf16
    unsigned short* Vtg = Qb + 16384 * 64;             // [8][64][2048] bf16 (V^T)
    float* out = (float*)d_out;

    wconv_kernel<<<dim3(32, 12), dim3(64), 0, stream>>>(Wk, Wq, Wv, Wf);
    proj_kernel<<<dim3(4096), dim3(64), 0, stream>>>(X, Wf, Kb, Qb, Vtg);
    attn_kernel<<<dim3(32, 8), dim3(512), 0, stream>>>(Kb, Qb, Vtg, out);
}

// Round 8
// 61.680 us; speedup vs baseline: 1.2958x; 1.2829x over previous
//
#include <hip/hip_runtime.h>

typedef __attribute__((ext_vector_type(8))) short short8;
typedef __attribute__((ext_vector_type(4))) short short4v;
typedef __attribute__((ext_vector_type(4))) float f32x4;

#define MFMA_16x16x32_BF16(A, B, C) __builtin_amdgcn_mfma_f32_16x16x32_bf16(A, B, C, 0, 0, 0)

// float -> bf16 bits, round-to-nearest-even (inputs always finite here)
__device__ __forceinline__ unsigned short f2bf(float x) {
    unsigned int u = __builtin_bit_cast(unsigned int, x);
    u = (u + 0x7FFFu + ((u >> 16) & 1u)) >> 16;
    return (unsigned short)u;
}

// ---------------------------------------------------------------------------
// Kernel 1: pack Wk|Wq|Wv (fp32 [1024][64]) -> Wt bf16 [192][1024] transposed,
// with the proj LDS bank-swizzle PRE-BAKED: within each 64-k tile, 8-short
// chunk c holds logical chunk c ^ (n&7).  (G21: global_load_lds writes LDS
// linearly, so the conflict-free permutation must come from the source.)
// ---------------------------------------------------------------------------
__global__ __launch_bounds__(256) void wconv_kernel(const float* __restrict__ Wk,
                                                    const float* __restrict__ Wq,
                                                    const float* __restrict__ Wv,
                                                    unsigned short* __restrict__ Wt) {
    const int n = blockIdx.x;                       // 0..191
    const float* W = (n < 64) ? Wk : (n < 128) ? Wq : Wv;
    const int col = n & 63;
    const int sw = (n & 7) << 3;
    for (int k = threadIdx.x; k < 1024; k += 256) {
        const int kd = (k & ~56) | ((k ^ sw) & 56);   // XOR chunk bits 3..5
        Wt[(size_t)n * 1024 + kd] = f2bf(W[(size_t)k * 64 + col]);
    }
}

// ---------------------------------------------------------------------------
// Kernel 2: QKV projection GEMM — round-5 glds structure, tile halved for TLP.
// BM=32, BN=96, BK=64; 256 thr = 4 waves (wr=w>>1 owns 16 rows, wc=w&1 owns
// a 48-col half).  Grid 1024 = 4 blocks/CU = 4 waves/SIMD (the lever this
// round: every prior proj ran at <=2 waves/SIMD and was latency-stalled).
// W staged LDS-linear via global_load_lds width=16 (source pre-swizzled by
// wconv; frag reads XOR by lr&7 -> conflict-free, 0 conflicts measured).
// A staged via regs (fp32->bf16) into 72-padded rows; next-tile A loads
// issued right after barrier 2, dependent convert after the MFMAs.
// Outputs: Kb/Qb row-major [16384][64]; V transposed Vtg[b][64][2048].
// ---------------------------------------------------------------------------
__global__ __launch_bounds__(256, 4) void proj_kernel(const float* __restrict__ X,
                                                      const unsigned short* __restrict__ Wt,
                                                      unsigned short* __restrict__ Kb,
                                                      unsigned short* __restrict__ Qb,
                                                      unsigned short* __restrict__ Vtg) {
    __shared__ __attribute__((aligned(16))) unsigned short Al[32 * 72];   // pad 64->72
    __shared__ __attribute__((aligned(16))) unsigned short Wl[96 * 64];   // linear (glds)
    const int t = threadIdx.x;
    const int w = t >> 6, lane = t & 63, lr = lane & 15, g = lane >> 4;
    const int wr = w >> 1, wc = w & 1;
    const int rt = blockIdx.x >> 1, cb = blockIdx.x & 1;
    const int r0 = rt * 32;
    const int n0 = cb * 96;

    f32x4 acc[3] = {};

    // A staging coords: row = t>>3 (0..31), chunk j = t&7 (8 floats)
    const int ar = t >> 3, aj = t & 7;
    const float* xsrc = X + (size_t)(r0 + ar) * 1024 + aj * 8;

    float4 a0 = *(const float4*)xsrc;
    float4 a1 = *(const float4*)(xsrc + 4);
    uint4 aw;
    aw.x = (unsigned)f2bf(a0.x) | ((unsigned)f2bf(a0.y) << 16);
    aw.y = (unsigned)f2bf(a0.z) | ((unsigned)f2bf(a0.w) << 16);
    aw.z = (unsigned)f2bf(a1.x) | ((unsigned)f2bf(a1.y) << 16);
    aw.w = (unsigned)f2bf(a1.z) | ((unsigned)f2bf(a1.w) << 16);

    for (int k0 = 0; k0 < 1024; k0 += 64) {
        __syncthreads();                          // (1) prev compute done with LDS
        // ---- W tile: 768 16B chunks, direct global->LDS, linear dest ----
#pragma unroll
        for (int i = 0; i < 3; ++i) {
            const int q = t + 256 * i;
            const unsigned short* src = Wt + (size_t)(n0 + (q >> 3)) * 1024 + k0 + (q & 7) * 8;
            __builtin_amdgcn_global_load_lds((const __attribute__((address_space(1))) void*)src,
                                             (__attribute__((address_space(3))) void*)&Wl[q * 8],
                                             16, 0, 0);
        }
        // ---- A tile: converted regs -> padded LDS ----
        *(uint4*)&Al[ar * 72 + aj * 8] = aw;
        __syncthreads();                          // (2) drains vmcnt+lgkm: tiles ready

        const bool more = (k0 + 64) < 1024;
        if (more) {                               // issue next A loads (hide under MFMAs)
            a0 = *(const float4*)(xsrc + k0 + 64);
            a1 = *(const float4*)(xsrc + k0 + 68);
        }

        // ---- compute ----
        short8 af[2];
        af[0] = *(const short8*)&Al[(16 * wr + lr) * 72 + 8 * g];
        af[1] = *(const short8*)&Al[(16 * wr + lr) * 72 + 32 + 8 * g];
#pragma unroll
        for (int c = 0; c < 3; ++c) {
            const int row = 48 * wc + 16 * c + lr;
#pragma unroll
            for (int sub = 0; sub < 2; ++sub) {
                const int cs = (4 * sub + g) ^ (lr & 7);     // un-swizzle
                short8 wf = *(const short8*)&Wl[row * 64 + cs * 8];
                acc[c] = MFMA_16x16x32_BF16(af[sub], wf, acc[c]);
            }
        }

        if (more) {                               // dependent convert AFTER compute
            aw.x = (unsigned)f2bf(a0.x) | ((unsigned)f2bf(a0.y) << 16);
            aw.y = (unsigned)f2bf(a0.z) | ((unsigned)f2bf(a0.w) << 16);
            aw.z = (unsigned)f2bf(a1.x) | ((unsigned)f2bf(a1.y) << 16);
            aw.w = (unsigned)f2bf(a1.z) | ((unsigned)f2bf(a1.w) << 16);
        }
    }

    // ---- epilogue: C/D layout col = lane&15 (W-col), row = 4*(lane>>4)+reg ----
    const int bb = r0 >> 11;                      // batch
    const int sb0 = (r0 & 2047) + 16 * wr + 4 * g;
    const int row = r0 + 16 * wr + 4 * g;
#pragma unroll
    for (int i = 0; i < 3; ++i) {
        const int cg = cb * 6 + wc * 3 + i;       // global col-tile 0..11
        if (cg < 4) {
#pragma unroll
            for (int r = 0; r < 4; ++r)
                Kb[(size_t)(row + r) * 64 + 16 * cg + lr] = f2bf(acc[i][r]);
        } else if (cg < 8) {
#pragma unroll
            for (int r = 0; r < 4; ++r)
                Qb[(size_t)(row + r) * 64 + 16 * (cg - 4) + lr] = f2bf(acc[i][r]);
        } else {
            const int h = 16 * (cg - 8) + lr;
            uint2 e;
            e.x = (unsigned)f2bf(acc[i][0]) | ((unsigned)f2bf(acc[i][1]) << 16);
            e.y = (unsigned)f2bf(acc[i][2]) | ((unsigned)f2bf(acc[i][3]) << 16);
            *(uint2*)(Vtg + (size_t)bb * 64 * 2048 + (size_t)h * 2048 + sb0) = e;
        }
    }
}

// ---------------------------------------------------------------------------
// Kernel 3: causal flash attention, band-pair blocks, 16 waves (4/SIMD).
// Block = bands {63-p (hi), p (lo)} of 32 q-rows each.  Waves 0-7 split the
// hi band's 64-p kv-steps; waves 8-15 split the lo band's p+1 steps (per-band
// split keeps kv0 <= q0 -> running max finite from each wave's first step;
// idle waves keep m=-inf -> weight 0 in the combine).  K and V^T fragments
// load DIRECTLY from global (L2-resident) -> no LDS/barriers in the loop.
// Partials merged in LDS at the end (16 slots, 143 KB -> 1 block/CU).
// ---------------------------------------------------------------------------
__global__ __launch_bounds__(1024, 4) void attn_kernel(const unsigned short* __restrict__ Kb,
                                                       const unsigned short* __restrict__ Qb,
                                                       const unsigned short* __restrict__ Vtg,
                                                       float* __restrict__ out) {
    __shared__ __attribute__((aligned(16))) float Pacc[16][32][68];  // [slot][q][h] pad 68
    __shared__ float Pml[2][16][32];                                 // m / l per slot,q

    const int t = threadIdx.x;
    const int w = t >> 6, lane = t & 63;
    const int lr = lane & 15, g = lane >> 4;
    const int p = blockIdx.x, b = blockIdx.y;
    const int band = w >> 3, wi = w & 7;
    const int nb = band ? (p + 1) : (64 - p);    // this band's kv-step count
    const int q0 = band ? p * 32 : (63 - p) * 32;
    const size_t rowbase = (size_t)b * 2048;
    const size_t vbase = (size_t)b * 64 * 2048;
    const float NEG_INF = -__builtin_inff();
    const float SCALE2 = 0.03125f * 1.4426950408889634f;   // d^-0.5 * log2(e)

    // Q fragments (B-operand): [sub][hh]
    short8 qf[2][2];
#pragma unroll
    for (int sub = 0; sub < 2; ++sub)
#pragma unroll
        for (int hh = 0; hh < 2; ++hh)
            qf[sub][hh] = *(const short8*)(Qb + (rowbase + q0 + 16 * sub + lr) * 64 + 32 * hh + 8 * g);

    f32x4 acc[2][4] = {};
    float m2[2] = {NEG_INF, NEG_INF};
    float ls[2] = {0.f, 0.f};

    const int s0 = (wi * nb) >> 3, s1 = ((wi + 1) * nb) >> 3;

    for (int s = s0; s < s1; ++s) {
        const int kv0 = s * 32;
        // K A-frags direct from global: row kv0+16f+lr, cols 32hh+8g (16B)
        short8 kf[2][2];
#pragma unroll
        for (int f = 0; f < 2; ++f)
#pragma unroll
            for (int hh = 0; hh < 2; ++hh)
                kf[f][hh] = *(const short8*)(Kb + (rowbase + kv0 + 16 * f + lr) * 64 + 32 * hh + 8 * g);
        // V^T A-frags direct from Vtg: row h=16fh+lr, kv cols 4g.. / 16+4g..
        short8 vf[4];
#pragma unroll
        for (int fh = 0; fh < 4; ++fh) {
            const unsigned short* vp = Vtg + vbase + (size_t)(16 * fh + lr) * 2048 + kv0 + 4 * g;
            short4v v0 = *(const short4v*)vp;
            short4v v1 = *(const short4v*)(vp + 16);
            short8 vv;
            vv[0] = v0[0]; vv[1] = v0[1]; vv[2] = v0[2]; vv[3] = v0[3];
            vv[4] = v1[0]; vv[5] = v1[1]; vv[6] = v1[2]; vv[7] = v1[3];
            vf[fh] = vv;
        }
#pragma unroll
        for (int sub = 0; sub < 2; ++sub) {
            f32x4 sv[2];
#pragma unroll
            for (int f = 0; f < 2; ++f) {
                f32x4 x = {};
                x = MFMA_16x16x32_BF16(kf[f][0], qf[sub][0], x);
                x = MFMA_16x16x32_BF16(kf[f][1], qf[sub][1], x);
                sv[f] = x;
            }
            const int q = q0 + 16 * sub + lr;
            float pvv[8], tmax = NEG_INF;
#pragma unroll
            for (int f = 0; f < 2; ++f)
#pragma unroll
                for (int r = 0; r < 4; ++r) {
                    int kp = kv0 + 16 * f + 4 * g + r;
                    float sc = sv[f][r] * SCALE2;
                    sc = (kp <= q) ? sc : NEG_INF;
                    pvv[4 * f + r] = sc;
                    tmax = fmaxf(tmax, sc);
                }
            tmax = fmaxf(tmax, __shfl_xor(tmax, 16));
            tmax = fmaxf(tmax, __shfl_xor(tmax, 32));
            float mnew = fmaxf(m2[sub], tmax);     // finite: kv0 <= q0 <= q always
            float alpha = exp2f(m2[sub] - mnew);
            float psum = 0.f;
            short8 pf;
#pragma unroll
            for (int e = 0; e < 8; ++e) {
                float pe = exp2f(pvv[e] - mnew);
                psum += pe;
                pf[e] = (short)f2bf(pe);
            }
            psum += __shfl_xor(psum, 16);
            psum += __shfl_xor(psum, 32);
            ls[sub] = ls[sub] * alpha + psum;
            m2[sub] = mnew;
#pragma unroll
            for (int fh = 0; fh < 4; ++fh) {
                acc[sub][fh][0] *= alpha; acc[sub][fh][1] *= alpha;
                acc[sub][fh][2] *= alpha; acc[sub][fh][3] *= alpha;
                acc[sub][fh] = MFMA_16x16x32_BF16(vf[fh], pf, acc[sub][fh]);
            }
        }
    }

    // ---- write partials to LDS: slot = band*8 + wi ----
    {
        const int slot = band * 8 + wi;
#pragma unroll
        for (int sub = 0; sub < 2; ++sub) {
#pragma unroll
            for (int fh = 0; fh < 4; ++fh)
                *(f32x4*)&Pacc[slot][16 * sub + lr][16 * fh + 4 * g] = acc[sub][fh];
            if (g == 0) {
                Pml[0][slot][16 * sub + lr] = m2[sub];
                Pml[1][slot][16 * sub + lr] = ls[sub];
            }
        }
    }
    __syncthreads();

    // ---- combine: 1024 thr -> 2 bands x 32 q x 16 h-quads ----
    {
        const int tb = t >> 9, t2 = t & 511;
        const int qq = t2 & 31, hb = (t2 >> 5) * 4;
        float mw[8], M = NEG_INF;
#pragma unroll
        for (int wv = 0; wv < 8; ++wv) {
            mw[wv] = Pml[0][tb * 8 + wv][qq];
            M = fmaxf(M, mw[wv]);
        }
        float wgt[8], L = 0.f;
#pragma unroll
        for (int wv = 0; wv < 8; ++wv) {
            wgt[wv] = exp2f(mw[wv] - M);           // exp2(-inf)=0 for idle waves
            L += wgt[wv] * Pml[1][tb * 8 + wv][qq];
        }
        f32x4 o = {};
#pragma unroll
        for (int wv = 0; wv < 8; ++wv)
            o += wgt[wv] * *(const f32x4*)&Pacc[tb * 8 + wv][qq][hb];
        o *= (1.f / L);
        const int qb = tb ? p * 32 : (63 - p) * 32;
        *(f32x4*)(out + (rowbase + qb + qq) * 64 + hb) = o;
    }
}

// ---------------------------------------------------------------------------
extern "C" void kernel_launch(void* const* d_in, const int* in_sizes, int n_in,
                              void* d_out, int out_size, void* d_ws, size_t ws_size,
                              hipStream_t stream) {
    const float* X  = (const float*)d_in[0];
    const float* Wk = (const float*)d_in[1];
    const float* Wq = (const float*)d_in[2];
    const float* Wv = (const float*)d_in[3];

    unsigned short* Wt  = (unsigned short*)d_ws;       // 192*1024 bf16 (swizzled)
    unsigned short* Kb  = Wt + 192 * 1024;             // [16384][64] bf16
    unsigned short* Qb  = Kb + 16384 * 64;             // [16384][64] bf16
    unsigned short* Vtg = Qb + 16384 * 64;             // [8][64][2048] bf16 (V^T)
    float* out = (float*)d_out;

    wconv_kernel<<<dim3(192), dim3(256), 0, stream>>>(Wk, Wq, Wv, Wt);
    proj_kernel<<<dim3(1024), dim3(256), 0, stream>>>(X, Wt, Kb, Qb, Vtg);
    attn_kernel<<<dim3(32, 8), dim3(1024), 0, stream>>>(Kb, Qb, Vtg, out);
}

// Round 9
// 55.837 us; speedup vs baseline: 1.4314x; 1.1046x over previous
//
#include <hip/hip_runtime.h>

typedef __attribute__((ext_vector_type(8))) short short8;
typedef __attribute__((ext_vector_type(4))) short short4v;
typedef __attribute__((ext_vector_type(4))) float f32x4;

#define MFMA_16x16x32_BF16(A, B, C) __builtin_amdgcn_mfma_f32_16x16x32_bf16(A, B, C, 0, 0, 0)

// float -> bf16 bits, round-to-nearest-even (inputs always finite here)
__device__ __forceinline__ unsigned short f2bf(float x) {
    unsigned int u = __builtin_bit_cast(unsigned int, x);
    u = (u + 0x7FFFu + ((u >> 16) & 1u)) >> 16;
    return (unsigned short)u;
}

// ---------------------------------------------------------------------------
// Kernel 1: pack Wk|Wq|Wv (fp32 [1024][64]) -> Wt bf16 [192][1024] transposed,
// with the proj LDS bank-swizzle PRE-BAKED: within each 64-k tile, 8-short
// chunk c holds logical chunk c ^ (n&7).  (G21: global_load_lds writes LDS
// linearly, so the conflict-free permutation must come from the source.)
// ---------------------------------------------------------------------------
__global__ __launch_bounds__(256) void wconv_kernel(const float* __restrict__ Wk,
                                                    const float* __restrict__ Wq,
                                                    const float* __restrict__ Wv,
                                                    unsigned short* __restrict__ Wt) {
    const int n = blockIdx.x;                       // 0..191
    const float* W = (n < 64) ? Wk : (n < 128) ? Wq : Wv;
    const int col = n & 63;
    const int sw = (n & 7) << 3;
    for (int k = threadIdx.x; k < 1024; k += 256) {
        const int kd = (k & ~56) | ((k ^ sw) & 56);   // XOR chunk bits 3..5
        Wt[(size_t)n * 1024 + kd] = f2bf(W[(size_t)k * 64 + col]);
    }
}

// ---------------------------------------------------------------------------
// Kernel 2: QKV projection GEMM — 2-phase single-barrier pipeline (catalog T3
// minimum).  BM=32, BN=192 (full, X read ONCE), BK=64; 512 thr = 8 waves
// (rw=w>>2 row-half, cw=w&3 col-quarter; 3 col-tiles x 2 k-subs = 6 MFMA).
// Grid 512 = 2 blocks/CU.  Per iter t:
//   [convert A(t+1) (drained by barrier -> no stall)]
//   [STAGE buf^1: ds_write A(t+1), glds W(t+1)]  <- full compute of slack
//   [issue A(t+2) -> fly regs]
//   [compute t from buf]
//   [ONE __syncthreads: drains W(t+1)/A(t+2) with compute+other-block slack]
// r8's failure mode (glds issued BETWEEN two barriers -> 0 slack) is gone.
// W LDS dbuf linear via glds width=16 (source pre-swizzled by wconv; frag
// reads XOR by lr&7 -> conflict-free).  Outputs: Kb/Qb [16384][64] row-major;
// V transposed Vtg[b][64][2048].
// ---------------------------------------------------------------------------
__global__ __launch_bounds__(512, 4) void proj_kernel(const float* __restrict__ X,
                                                      const unsigned short* __restrict__ Wt,
                                                      unsigned short* __restrict__ Kb,
                                                      unsigned short* __restrict__ Qb,
                                                      unsigned short* __restrict__ Vtg) {
    __shared__ __attribute__((aligned(16))) unsigned short Wl[2][192 * 64];  // glds dbuf
    __shared__ __attribute__((aligned(16))) unsigned short Al[2][32 * 72];   // pad 64->72
    const int t = threadIdx.x;
    const int w = t >> 6, lane = t & 63, lr = lane & 15, g = lane >> 4;
    const int rw = w >> 2, cw = w & 3;
    const int r0 = blockIdx.x * 32;

    f32x4 acc[3] = {};

    // A staging coords: row = t>>4 (0..31), chunk = t&15 (4 floats)
    const int ar = t >> 4, ac = (t & 15) * 4;
    const float* xsrc = X + (size_t)(r0 + ar) * 1024 + ac;

    // ---- prologue ----
    float4 fly = *(const float4*)xsrc;                     // A(0)
    uint2 aw;
    aw.x = (unsigned)f2bf(fly.x) | ((unsigned)f2bf(fly.y) << 16);
    aw.y = (unsigned)f2bf(fly.z) | ((unsigned)f2bf(fly.w) << 16);
    *(uint2*)&Al[0][ar * 72 + ac] = aw;
#pragma unroll
    for (int i = 0; i < 3; ++i) {                          // W(0) -> Wl[0]
        const int q = t + 512 * i;
        const unsigned short* src = Wt + (size_t)(q >> 3) * 1024 + (q & 7) * 8;
        __builtin_amdgcn_global_load_lds((const __attribute__((address_space(1))) void*)src,
                                         (__attribute__((address_space(3))) void*)&Wl[0][q * 8],
                                         16, 0, 0);
    }
    fly = *(const float4*)(xsrc + 64);                     // A(1)
    __syncthreads();                                       // tiles t=0 ready

    for (int t16 = 0; t16 < 16; ++t16) {
        const int cur = t16 & 1;
        // ---- convert A(t+1): loads drained by the barrier -> no stall ----
        if (t16 < 15) {
            aw.x = (unsigned)f2bf(fly.x) | ((unsigned)f2bf(fly.y) << 16);
            aw.y = (unsigned)f2bf(fly.z) | ((unsigned)f2bf(fly.w) << 16);
            // ---- STAGE buf^1: A(t+1) write + W(t+1) glds ----
            *(uint2*)&Al[cur ^ 1][ar * 72 + ac] = aw;
            const int k1 = (t16 + 1) * 64;
#pragma unroll
            for (int i = 0; i < 3; ++i) {
                const int q = t + 512 * i;
                const unsigned short* src = Wt + (size_t)(q >> 3) * 1024 + k1 + (q & 7) * 8;
                __builtin_amdgcn_global_load_lds((const __attribute__((address_space(1))) void*)src,
                                                 (__attribute__((address_space(3))) void*)&Wl[cur ^ 1][q * 8],
                                                 16, 0, 0);
            }
        }
        // ---- issue A(t+2) ----
        if (t16 < 14) fly = *(const float4*)(xsrc + (t16 + 2) * 64);

        // ---- compute tile t from buf cur ----
        short8 af[2];
        af[0] = *(const short8*)&Al[cur][(16 * rw + lr) * 72 + 8 * g];
        af[1] = *(const short8*)&Al[cur][(16 * rw + lr) * 72 + 32 + 8 * g];
#pragma unroll
        for (int c = 0; c < 3; ++c) {
            const int row = 48 * cw + 16 * c + lr;
#pragma unroll
            for (int sub = 0; sub < 2; ++sub) {
                const int cs = (4 * sub + g) ^ (lr & 7);     // un-swizzle
                short8 wf = *(const short8*)&Wl[cur][row * 64 + cs * 8];
                acc[c] = MFMA_16x16x32_BF16(af[sub], wf, acc[c]);
            }
        }
        __syncthreads();                           // ONE barrier per step
    }

    // ---- epilogue: C/D layout col = lane&15 (W-col), row = 4*(lane>>4)+reg ----
    const int bb = r0 >> 11;                      // batch
    const int sb0 = (r0 & 2047) + 16 * rw + 4 * g;
    const int row = r0 + 16 * rw + 4 * g;
#pragma unroll
    for (int i = 0; i < 3; ++i) {
        const int cg = cw * 3 + i;                // global col-tile 0..11
        if (cg < 4) {
#pragma unroll
            for (int r = 0; r < 4; ++r)
                Kb[(size_t)(row + r) * 64 + 16 * cg + lr] = f2bf(acc[i][r]);
        } else if (cg < 8) {
#pragma unroll
            for (int r = 0; r < 4; ++r)
                Qb[(size_t)(row + r) * 64 + 16 * (cg - 4) + lr] = f2bf(acc[i][r]);
        } else {
            const int h = 16 * (cg - 8) + lr;
            uint2 e;
            e.x = (unsigned)f2bf(acc[i][0]) | ((unsigned)f2bf(acc[i][1]) << 16);
            e.y = (unsigned)f2bf(acc[i][2]) | ((unsigned)f2bf(acc[i][3]) << 16);
            *(uint2*)(Vtg + (size_t)bb * 64 * 2048 + (size_t)h * 2048 + sb0) = e;
        }
    }
}

// ---------------------------------------------------------------------------
// Kernel 3: causal flash attention, band-pair blocks, 16 waves (unchanged).
// Block = bands {63-p (hi), p (lo)} of 32 q-rows each.  Waves 0-7 split the
// hi band's 64-p kv-steps; waves 8-15 split the lo band's p+1 steps.
// K and V^T fragments load DIRECTLY from global (L2-resident).
// Partials merged in LDS at the end (16 slots).
// ---------------------------------------------------------------------------
__global__ __launch_bounds__(1024, 4) void attn_kernel(const unsigned short* __restrict__ Kb,
                                                       const unsigned short* __restrict__ Qb,
                                                       const unsigned short* __restrict__ Vtg,
                                                       float* __restrict__ out) {
    __shared__ __attribute__((aligned(16))) float Pacc[16][32][68];  // [slot][q][h] pad 68
    __shared__ float Pml[2][16][32];                                 // m / l per slot,q

    const int t = threadIdx.x;
    const int w = t >> 6, lane = t & 63;
    const int lr = lane & 15, g = lane >> 4;
    const int p = blockIdx.x, b = blockIdx.y;
    const int band = w >> 3, wi = w & 7;
    const int nb = band ? (p + 1) : (64 - p);    // this band's kv-step count
    const int q0 = band ? p * 32 : (63 - p) * 32;
    const size_t rowbase = (size_t)b * 2048;
    const size_t vbase = (size_t)b * 64 * 2048;
    const float NEG_INF = -__builtin_inff();
    const float SCALE2 = 0.03125f * 1.4426950408889634f;   // d^-0.5 * log2(e)

    // Q fragments (B-operand): [sub][hh]
    short8 qf[2][2];
#pragma unroll
    for (int sub = 0; sub < 2; ++sub)
#pragma unroll
        for (int hh = 0; hh < 2; ++hh)
            qf[sub][hh] = *(const short8*)(Qb + (rowbase + q0 + 16 * sub + lr) * 64 + 32 * hh + 8 * g);

    f32x4 acc[2][4] = {};
    float m2[2] = {NEG_INF, NEG_INF};
    float ls[2] = {0.f, 0.f};

    const int s0 = (wi * nb) >> 3, s1 = ((wi + 1) * nb) >> 3;

    for (int s = s0; s < s1; ++s) {
        const int kv0 = s * 32;
        // K A-frags direct from global: row kv0+16f+lr, cols 32hh+8g (16B)
        short8 kf[2][2];
#pragma unroll
        for (int f = 0; f < 2; ++f)
#pragma unroll
            for (int hh = 0; hh < 2; ++hh)
                kf[f][hh] = *(const short8*)(Kb + (rowbase + kv0 + 16 * f + lr) * 64 + 32 * hh + 8 * g);
        // V^T A-frags direct from Vtg: row h=16fh+lr, kv cols 4g.. / 16+4g..
        short8 vf[4];
#pragma unroll
        for (int fh = 0; fh < 4; ++fh) {
            const unsigned short* vp = Vtg + vbase + (size_t)(16 * fh + lr) * 2048 + kv0 + 4 * g;
            short4v v0 = *(const short4v*)vp;
            short4v v1 = *(const short4v*)(vp + 16);
            short8 vv;
            vv[0] = v0[0]; vv[1] = v0[1]; vv[2] = v0[2]; vv[3] = v0[3];
            vv[4] = v1[0]; vv[5] = v1[1]; vv[6] = v1[2]; vv[7] = v1[3];
            vf[fh] = vv;
        }
#pragma unroll
        for (int sub = 0; sub < 2; ++sub) {
            f32x4 sv[2];
#pragma unroll
            for (int f = 0; f < 2; ++f) {
                f32x4 x = {};
                x = MFMA_16x16x32_BF16(kf[f][0], qf[sub][0], x);
                x = MFMA_16x16x32_BF16(kf[f][1], qf[sub][1], x);
                sv[f] = x;
            }
            const int q = q0 + 16 * sub + lr;
            float pvv[8], tmax = NEG_INF;
#pragma unroll
            for (int f = 0; f < 2; ++f)
#pragma unroll
                for (int r = 0; r < 4; ++r) {
                    int kp = kv0 + 16 * f + 4 * g + r;
                    float sc = sv[f][r] * SCALE2;
                    sc = (kp <= q) ? sc : NEG_INF;
                    pvv[4 * f + r] = sc;
                    tmax = fmaxf(tmax, sc);
                }
            tmax = fmaxf(tmax, __shfl_xor(tmax, 16));
            tmax = fmaxf(tmax, __shfl_xor(tmax, 32));
            float mnew = fmaxf(m2[sub], tmax);     // finite: kv0 <= q0 <= q always
            float alpha = exp2f(m2[sub] - mnew);
            float psum = 0.f;
            short8 pf;
#pragma unroll
            for (int e = 0; e < 8; ++e) {
                float pe = exp2f(pvv[e] - mnew);
                psum += pe;
                pf[e] = (short)f2bf(pe);
            }
            psum += __shfl_xor(psum, 16);
            psum += __shfl_xor(psum, 32);
            ls[sub] = ls[sub] * alpha + psum;
            m2[sub] = mnew;
#pragma unroll
            for (int fh = 0; fh < 4; ++fh) {
                acc[sub][fh][0] *= alpha; acc[sub][fh][1] *= alpha;
                acc[sub][fh][2] *= alpha; acc[sub][fh][3] *= alpha;
                acc[sub][fh] = MFMA_16x16x32_BF16(vf[fh], pf, acc[sub][fh]);
            }
        }
    }

    // ---- write partials to LDS: slot = band*8 + wi ----
    {
        const int slot = band * 8 + wi;
#pragma unroll
        for (int sub = 0; sub < 2; ++sub) {
#pragma unroll
            for (int fh = 0; fh < 4; ++fh)
                *(f32x4*)&Pacc[slot][16 * sub + lr][16 * fh + 4 * g] = acc[sub][fh];
            if (g == 0) {
                Pml[0][slot][16 * sub + lr] = m2[sub];
                Pml[1][slot][16 * sub + lr] = ls[sub];
            }
        }
    }
    __syncthreads();

    // ---- combine: 1024 thr -> 2 bands x 32 q x 16 h-quads ----
    {
        const int tb = t >> 9, t2 = t & 511;
        const int qq = t2 & 31, hb = (t2 >> 5) * 4;
        float mw[8], M = NEG_INF;
#pragma unroll
        for (int wv = 0; wv < 8; ++wv) {
            mw[wv] = Pml[0][tb * 8 + wv][qq];
            M = fmaxf(M, mw[wv]);
        }
        float wgt[8], L = 0.f;
#pragma unroll
        for (int wv = 0; wv < 8; ++wv) {
            wgt[wv] = exp2f(mw[wv] - M);           // exp2(-inf)=0 for idle waves
            L += wgt[wv] * Pml[1][tb * 8 + wv][qq];
        }
        f32x4 o = {};
#pragma unroll
        for (int wv = 0; wv < 8; ++wv)
            o += wgt[wv] * *(const f32x4*)&Pacc[tb * 8 + wv][qq][hb];
        o *= (1.f / L);
        const int qb = tb ? p * 32 : (63 - p) * 32;
        *(f32x4*)(out + (rowbase + qb + qq) * 64 + hb) = o;
    }
}

// ---------------------------------------------------------------------------
extern "C" void kernel_launch(void* const* d_in, const int* in_sizes, int n_in,
                              void* d_out, int out_size, void* d_ws, size_t ws_size,
                              hipStream_t stream) {
    const float* X  = (const float*)d_in[0];
    const float* Wk = (const float*)d_in[1];
    const float* Wq = (const float*)d_in[2];
    const float* Wv = (const float*)d_in[3];

    unsigned short* Wt  = (unsigned short*)d_ws;       // 192*1024 bf16 (swizzled)
    unsigned short* Kb  = Wt + 192 * 1024;             // [16384][64] bf16
    unsigned short* Qb  = Kb + 16384 * 64;             // [16384][64] bf16
    unsigned short* Vtg = Qb + 16384 * 64;             // [8][64][2048] bf16 (V^T)
    float* out = (float*)d_out;

    wconv_kernel<<<dim3(192), dim3(256), 0, stream>>>(Wk, Wq, Wv, Wt);
    proj_kernel<<<dim3(512), dim3(512), 0, stream>>>(X, Wt, Kb, Qb, Vtg);
    attn_kernel<<<dim3(32, 8), dim3(1024), 0, stream>>>(Kb, Qb, Vtg, out);
}

// Round 10
// 54.972 us; speedup vs baseline: 1.4540x; 1.0157x over previous
//
#include <hip/hip_runtime.h>

typedef __attribute__((ext_vector_type(8))) short short8;
typedef __attribute__((ext_vector_type(4))) short short4v;
typedef __attribute__((ext_vector_type(4))) float f32x4;

#define MFMA_16x16x32_BF16(A, B, C) __builtin_amdgcn_mfma_f32_16x16x32_bf16(A, B, C, 0, 0, 0)

// float -> bf16 bits, round-to-nearest-even (inputs always finite here)
__device__ __forceinline__ unsigned short f2bf(float x) {
    unsigned int u = __builtin_bit_cast(unsigned int, x);
    u = (u + 0x7FFFu + ((u >> 16) & 1u)) >> 16;
    return (unsigned short)u;
}

// ---------------------------------------------------------------------------
// Kernel 1: pack Wk|Wq|Wv (fp32 [1024][64]) -> Wt bf16 [192][1024] transposed,
// with the proj LDS bank-swizzle PRE-BAKED: within each 64-k tile, 8-short
// chunk c holds logical chunk c ^ (n&7).  (G21: global_load_lds writes LDS
// linearly, so the conflict-free permutation must come from the source.)
// ---------------------------------------------------------------------------
__global__ __launch_bounds__(256) void wconv_kernel(const float* __restrict__ Wk,
                                                    const float* __restrict__ Wq,
                                                    const float* __restrict__ Wv,
                                                    unsigned short* __restrict__ Wt) {
    const int n = blockIdx.x;                       // 0..191
    const float* W = (n < 64) ? Wk : (n < 128) ? Wq : Wv;
    const int col = n & 63;
    const int sw = (n & 7) << 3;
    for (int k = threadIdx.x; k < 1024; k += 256) {
        const int kd = (k & ~56) | ((k ^ sw) & 56);   // XOR chunk bits 3..5
        Wt[(size_t)n * 1024 + kd] = f2bf(W[(size_t)k * 64 + col]);
    }
}

// ---------------------------------------------------------------------------
// Kernel 2: QKV projection GEMM — 2-phase pipeline with COUNTED-VMCNT barrier
// (catalog T4).  BM=32, BN=192, BK=64; 512 thr = 8 waves; grid 512 = 2
// blocks/CU.  Per iter t:
//   [convert A(t+1): compiler's exact-count wait drains only that load]
//   [STAGE buf^1: ds_write A(t+1), glds W(t+1) x3]
//   [sched_barrier -> pin issue order]
//   [issue A(t+2) (clamped at tail so the count invariant holds)]
//   [compute t from buf]
//   [s_waitcnt vmcnt(1) lgkmcnt(0); s_barrier]   <- W glds drained, A prefetch
//                                                   STAYS IN FLIGHT across the
//                                                   barrier (the T4 lever; a
//                                                   __syncthreads would drain
//                                                   it and cap X streaming at
//                                                   ~1/3 duty cycle = r9's 3x)
// W LDS dbuf linear via glds width=16 (source pre-swizzled by wconv; frag
// reads XOR by lr&7 -> conflict-free).  Outputs: Kb/Qb [16384][64] row-major;
// V transposed Vtg[b][64][2048].
// ---------------------------------------------------------------------------
__global__ __launch_bounds__(512, 4) void proj_kernel(const float* __restrict__ X,
                                                      const unsigned short* __restrict__ Wt,
                                                      unsigned short* __restrict__ Kb,
                                                      unsigned short* __restrict__ Qb,
                                                      unsigned short* __restrict__ Vtg) {
    __shared__ __attribute__((aligned(16))) unsigned short Wl[2][192 * 64];  // glds dbuf
    __shared__ __attribute__((aligned(16))) unsigned short Al[2][32 * 72];   // pad 64->72
    const int t = threadIdx.x;
    const int w = t >> 6, lane = t & 63, lr = lane & 15, g = lane >> 4;
    const int rw = w >> 2, cw = w & 3;
    const int r0 = blockIdx.x * 32;

    f32x4 acc[3] = {};

    // A staging coords: row = t>>4 (0..31), chunk = t&15 (4 floats)
    const int ar = t >> 4, ac = (t & 15) * 4;
    const float* xsrc = X + (size_t)(r0 + ar) * 1024 + ac;

    // ---- prologue ----
    float4 fly = *(const float4*)xsrc;                     // A(0)
    uint2 aw;
    aw.x = (unsigned)f2bf(fly.x) | ((unsigned)f2bf(fly.y) << 16);
    aw.y = (unsigned)f2bf(fly.z) | ((unsigned)f2bf(fly.w) << 16);
    *(uint2*)&Al[0][ar * 72 + ac] = aw;
#pragma unroll
    for (int i = 0; i < 3; ++i) {                          // W(0) -> Wl[0]
        const int q = t + 512 * i;
        const unsigned short* src = Wt + (size_t)(q >> 3) * 1024 + (q & 7) * 8;
        __builtin_amdgcn_global_load_lds((const __attribute__((address_space(1))) void*)src,
                                         (__attribute__((address_space(3))) void*)&Wl[0][q * 8],
                                         16, 0, 0);
    }
    __builtin_amdgcn_sched_barrier(0);                     // keep A-issue younger than glds
    fly = *(const float4*)(xsrc + 64);                     // A(1) — flies across barrier
    asm volatile("s_waitcnt vmcnt(1) lgkmcnt(0)" ::: "memory");
    __builtin_amdgcn_s_barrier();                          // tiles t=0 ready

    for (int t16 = 0; t16 < 16; ++t16) {
        const int cur = t16 & 1;
        if (t16 < 15) {
            // ---- convert A(t+1): auto-wait drains exactly that load ----
            aw.x = (unsigned)f2bf(fly.x) | ((unsigned)f2bf(fly.y) << 16);
            aw.y = (unsigned)f2bf(fly.z) | ((unsigned)f2bf(fly.w) << 16);
            // ---- STAGE buf^1: A(t+1) write + W(t+1) glds ----
            *(uint2*)&Al[cur ^ 1][ar * 72 + ac] = aw;
            const int k1 = (t16 + 1) * 64;
#pragma unroll
            for (int i = 0; i < 3; ++i) {
                const int q = t + 512 * i;
                const unsigned short* src = Wt + (size_t)(q >> 3) * 1024 + k1 + (q & 7) * 8;
                __builtin_amdgcn_global_load_lds((const __attribute__((address_space(1))) void*)src,
                                                 (__attribute__((address_space(3))) void*)&Wl[cur ^ 1][q * 8],
                                                 16, 0, 0);
            }
            __builtin_amdgcn_sched_barrier(0);             // pin: glds older than A-issue
            // ---- issue A(t+2); clamped at tail so vmcnt(1) always leaves
            //      exactly the A prefetch (never a glds) outstanding ----
            const int anext = (t16 + 2 < 15) ? (t16 + 2) : 15;
            fly = *(const float4*)(xsrc + anext * 64);
        }

        // ---- compute tile t from buf cur ----
        short8 af[2];
        af[0] = *(const short8*)&Al[cur][(16 * rw + lr) * 72 + 8 * g];
        af[1] = *(const short8*)&Al[cur][(16 * rw + lr) * 72 + 32 + 8 * g];
#pragma unroll
        for (int c = 0; c < 3; ++c) {
            const int row = 48 * cw + 16 * c + lr;
#pragma unroll
            for (int sub = 0; sub < 2; ++sub) {
                const int cs = (4 * sub + g) ^ (lr & 7);     // un-swizzle
                short8 wf = *(const short8*)&Wl[cur][row * 64 + cs * 8];
                acc[c] = MFMA_16x16x32_BF16(af[sub], wf, acc[c]);
            }
        }
        // ---- counted-vmcnt barrier: W(t+1) drained, A prefetch stays live ----
        asm volatile("s_waitcnt vmcnt(1) lgkmcnt(0)" ::: "memory");
        __builtin_amdgcn_s_barrier();
    }

    // ---- epilogue: C/D layout col = lane&15 (W-col), row = 4*(lane>>4)+reg ----
    const int bb = r0 >> 11;                      // batch
    const int sb0 = (r0 & 2047) + 16 * rw + 4 * g;
    const int row = r0 + 16 * rw + 4 * g;
#pragma unroll
    for (int i = 0; i < 3; ++i) {
        const int cg = cw * 3 + i;                // global col-tile 0..11
        if (cg < 4) {
#pragma unroll
            for (int r = 0; r < 4; ++r)
                Kb[(size_t)(row + r) * 64 + 16 * cg + lr] = f2bf(acc[i][r]);
        } else if (cg < 8) {
#pragma unroll
            for (int r = 0; r < 4; ++r)
                Qb[(size_t)(row + r) * 64 + 16 * (cg - 4) + lr] = f2bf(acc[i][r]);
        } else {
            const int h = 16 * (cg - 8) + lr;
            uint2 e;
            e.x = (unsigned)f2bf(acc[i][0]) | ((unsigned)f2bf(acc[i][1]) << 16);
            e.y = (unsigned)f2bf(acc[i][2]) | ((unsigned)f2bf(acc[i][3]) << 16);
            *(uint2*)(Vtg + (size_t)bb * 64 * 2048 + (size_t)h * 2048 + sb0) = e;
        }
    }
}

// ---------------------------------------------------------------------------
// Kernel 3: causal flash attention, band-pair blocks, 16 waves (unchanged).
// Block = bands {63-p (hi), p (lo)} of 32 q-rows each.  Waves 0-7 split the
// hi band's 64-p kv-steps; waves 8-15 split the lo band's p+1 steps.
// K and V^T fragments load DIRECTLY from global (L2-resident).
// Partials merged in LDS at the end (16 slots).
// ---------------------------------------------------------------------------
__global__ __launch_bounds__(1024, 4) void attn_kernel(const unsigned short* __restrict__ Kb,
                                                       const unsigned short* __restrict__ Qb,
                                                       const unsigned short* __restrict__ Vtg,
                                                       float* __restrict__ out) {
    __shared__ __attribute__((aligned(16))) float Pacc[16][32][68];  // [slot][q][h] pad 68
    __shared__ float Pml[2][16][32];                                 // m / l per slot,q

    const int t = threadIdx.x;
    const int w = t >> 6, lane = t & 63;
    const int lr = lane & 15, g = lane >> 4;
    const int p = blockIdx.x, b = blockIdx.y;
    const int band = w >> 3, wi = w & 7;
    const int nb = band ? (p + 1) : (64 - p);    // this band's kv-step count
    const int q0 = band ? p * 32 : (63 - p) * 32;
    const size_t rowbase = (size_t)b * 2048;
    const size_t vbase = (size_t)b * 64 * 2048;
    const float NEG_INF = -__builtin_inff();
    const float SCALE2 = 0.03125f * 1.4426950408889634f;   // d^-0.5 * log2(e)

    // Q fragments (B-operand): [sub][hh]
    short8 qf[2][2];
#pragma unroll
    for (int sub = 0; sub < 2; ++sub)
#pragma unroll
        for (int hh = 0; hh < 2; ++hh)
            qf[sub][hh] = *(const short8*)(Qb + (rowbase + q0 + 16 * sub + lr) * 64 + 32 * hh + 8 * g);

    f32x4 acc[2][4] = {};
    float m2[2] = {NEG_INF, NEG_INF};
    float ls[2] = {0.f, 0.f};

    const int s0 = (wi * nb) >> 3, s1 = ((wi + 1) * nb) >> 3;

    for (int s = s0; s < s1; ++s) {
        const int kv0 = s * 32;
        // K A-frags direct from global: row kv0+16f+lr, cols 32hh+8g (16B)
        short8 kf[2][2];
#pragma unroll
        for (int f = 0; f < 2; ++f)
#pragma unroll
            for (int hh = 0; hh < 2; ++hh)
                kf[f][hh] = *(const short8*)(Kb + (rowbase + kv0 + 16 * f + lr) * 64 + 32 * hh + 8 * g);
        // V^T A-frags direct from Vtg: row h=16fh+lr, kv cols 4g.. / 16+4g..
        short8 vf[4];
#pragma unroll
        for (int fh = 0; fh < 4; ++fh) {
            const unsigned short* vp = Vtg + vbase + (size_t)(16 * fh + lr) * 2048 + kv0 + 4 * g;
            short4v v0 = *(const short4v*)vp;
            short4v v1 = *(const short4v*)(vp + 16);
            short8 vv;
            vv[0] = v0[0]; vv[1] = v0[1]; vv[2] = v0[2]; vv[3] = v0[3];
            vv[4] = v1[0]; vv[5] = v1[1]; vv[6] = v1[2]; vv[7] = v1[3];
            vf[fh] = vv;
        }
#pragma unroll
        for (int sub = 0; sub < 2; ++sub) {
            f32x4 sv[2];
#pragma unroll
            for (int f = 0; f < 2; ++f) {
                f32x4 x = {};
                x = MFMA_16x16x32_BF16(kf[f][0], qf[sub][0], x);
                x = MFMA_16x16x32_BF16(kf[f][1], qf[sub][1], x);
                sv[f] = x;
            }
            const int q = q0 + 16 * sub + lr;
            float pvv[8], tmax = NEG_INF;
#pragma unroll
            for (int f = 0; f < 2; ++f)
#pragma unroll
                for (int r = 0; r < 4; ++r) {
                    int kp = kv0 + 16 * f + 4 * g + r;
                    float sc = sv[f][r] * SCALE2;
                    sc = (kp <= q) ? sc : NEG_INF;
                    pvv[4 * f + r] = sc;
                    tmax = fmaxf(tmax, sc);
                }
            tmax = fmaxf(tmax, __shfl_xor(tmax, 16));
            tmax = fmaxf(tmax, __shfl_xor(tmax, 32));
            float mnew = fmaxf(m2[sub], tmax);     // finite: kv0 <= q0 <= q always
            float alpha = exp2f(m2[sub] - mnew);
            float psum = 0.f;
            short8 pf;
#pragma unroll
            for (int e = 0; e < 8; ++e) {
                float pe = exp2f(pvv[e] - mnew);
                psum += pe;
                pf[e] = (short)f2bf(pe);
            }
            psum += __shfl_xor(psum, 16);
            psum += __shfl_xor(psum, 32);
            ls[sub] = ls[sub] * alpha + psum;
            m2[sub] = mnew;
#pragma unroll
            for (int fh = 0; fh < 4; ++fh) {
                acc[sub][fh][0] *= alpha; acc[sub][fh][1] *= alpha;
                acc[sub][fh][2] *= alpha; acc[sub][fh][3] *= alpha;
                acc[sub][fh] = MFMA_16x16x32_BF16(vf[fh], pf, acc[sub][fh]);
            }
        }
    }

    // ---- write partials to LDS: slot = band*8 + wi ----
    {
        const int slot = band * 8 + wi;
#pragma unroll
        for (int sub = 0; sub < 2; ++sub) {
#pragma unroll
            for (int fh = 0; fh < 4; ++fh)
                *(f32x4*)&Pacc[slot][16 * sub + lr][16 * fh + 4 * g] = acc[sub][fh];
            if (g == 0) {
                Pml[0][slot][16 * sub + lr] = m2[sub];
                Pml[1][slot][16 * sub + lr] = ls[sub];
            }
        }
    }
    __syncthreads();

    // ---- combine: 1024 thr -> 2 bands x 32 q x 16 h-quads ----
    {
        const int tb = t >> 9, t2 = t & 511;
        const int qq = t2 & 31, hb = (t2 >> 5) * 4;
        float mw[8], M = NEG_INF;
#pragma unroll
        for (int wv = 0; wv < 8; ++wv) {
            mw[wv] = Pml[0][tb * 8 + wv][qq];
            M = fmaxf(M, mw[wv]);
        }
        float wgt[8], L = 0.f;
#pragma unroll
        for (int wv = 0; wv < 8; ++wv) {
            wgt[wv] = exp2f(mw[wv] - M);           // exp2(-inf)=0 for idle waves
            L += wgt[wv] * Pml[1][tb * 8 + wv][qq];
        }
        f32x4 o = {};
#pragma unroll
        for (int wv = 0; wv < 8; ++wv)
            o += wgt[wv] * *(const f32x4*)&Pacc[tb * 8 + wv][qq][hb];
        o *= (1.f / L);
        const int qb = tb ? p * 32 : (63 - p) * 32;
        *(f32x4*)(out + (rowbase + qb + qq) * 64 + hb) = o;
    }
}

// ---------------------------------------------------------------------------
extern "C" void kernel_launch(void* const* d_in, const int* in_sizes, int n_in,
                              void* d_out, int out_size, void* d_ws, size_t ws_size,
                              hipStream_t stream) {
    const float* X  = (const float*)d_in[0];
    const float* Wk = (const float*)d_in[1];
    const float* Wq = (const float*)d_in[2];
    const float* Wv = (const float*)d_in[3];

    unsigned short* Wt  = (unsigned short*)d_ws;       // 192*1024 bf16 (swizzled)
    unsigned short* Kb  = Wt + 192 * 1024;             // [16384][64] bf16
    unsigned short* Qb  = Kb + 16384 * 64;             // [16384][64] bf16
    unsigned short* Vtg = Qb + 16384 * 64;             // [8][64][2048] bf16 (V^T)
    float* out = (float*)d_out;

    wconv_kernel<<<dim3(192), dim3(256), 0, stream>>>(Wk, Wq, Wv, Wt);
    proj_kernel<<<dim3(512), dim3(512), 0, stream>>>(X, Wt, Kb, Qb, Vtg);
    attn_kernel<<<dim3(32, 8), dim3(1024), 0, stream>>>(Kb, Qb, Vtg, out);
}